// Round 1
// 271.707 us; speedup vs baseline: 1.1394x; 1.1394x over previous
//
#include <hip/hip_runtime.h>

#define LVLS  16
#define TSZ   524288u          // 2^19
#define TMASK (TSZ - 1u)
#define PRIME 2654435761u

// floor(16 * g^l), g = 128^(1/15) — matches np float64 floor then f32 cast
__constant__ float RES[LVLS] = {16.f, 22.f, 30.f, 42.f, 58.f, 80.f, 111.f, 153.f,
                                212.f, 294.f, 406.f, 561.f, 776.f, 1072.f, 1482.f, 2048.f};

typedef __bf16 bf16x8 __attribute__((ext_vector_type(8)));
typedef float  f32x4  __attribute__((ext_vector_type(4)));

union Frag {
    uint4          q;
    unsigned       u[4];
    unsigned short s[8];
    bf16x8         v;
};

static __device__ __forceinline__ unsigned short f2bf(float f) {
    unsigned u = __float_as_uint(f);
    u += 0x7FFFu + ((u >> 16) & 1u);          // RNE; inputs finite, non-NaN
    return (unsigned short)(u >> 16);
}
static __device__ __forceinline__ unsigned pack2(float a, float b) {
    return (unsigned)f2bf(a) | ((unsigned)f2bf(b) << 16);
}
// order LDS phases without cross-wave barriers (per-wave scratch only)
static __device__ __forceinline__ void lds_fence() {
    asm volatile("s_waitcnt lgkmcnt(0)" ::: "memory");
}

// ============ fused encode + MLP ============
// Block = 512 threads = 8 waves = 512 points. Each thread hash-encodes its
// point across all 16 levels into LDS (sfeat), then each wave runs the
// MFMA MLP on its own 64 points (4 tiles of 16). No global feat array.
// Layouts (m89/m120-verified): A[m=lane&15][k=quad*8+j], B[k=quad*8+j][n=lane&15],
// C/D col=lane&15 row=quad*4+reg.
__global__ __launch_bounds__(512, 4) void ngp_fused(
    const float* __restrict__ x, const float* __restrict__ tables,
    const float* __restrict__ W0, const float* __restrict__ b0,
    const float* __restrict__ W1, const float* __restrict__ b1,
    const float* __restrict__ W2, const float* __restrict__ b2,
    float* __restrict__ out, int N)
{
    __shared__ uint4 sB0[4 * 64];     // W0 32x64 -> 4 col-tiles of B frags (4 KB)
    __shared__ uint4 sB1[8 * 64];     // W1 64x64 -> 2 k-tiles x 4 col-tiles (8 KB)
    // sfeat[w][lvl][col]: col XOR-swizzled by (lvl>>2)&3 so the A0 read
    // (4 quads at same 16-col window) spreads across all 32 banks (2 lanes/bank).
    __shared__ unsigned sfeat[8][LVLS][64];                   // 32 KB
    __shared__ __align__(16) unsigned short hscr[8][16][72];  // per-wave, pitch 72 (18 KB)

    const int tid  = threadIdx.x;
    const int lane = tid & 63;
    const int w    = tid >> 6;       // wave 0..7
    const int c    = lane & 15;
    const int quad = lane >> 4;

    // ---- build B fragments in LDS (bf16, B-operand layout) ----
    {
        const int f = w;             // 0..7
        if (f < 4) {
            Frag t0;
            #pragma unroll
            for (int j = 0; j < 8; ++j)
                t0.s[j] = f2bf(W0[(quad * 8 + j) * 64 + f * 16 + c]);
            sB0[f * 64 + lane] = t0.q;
        }
        {
            const int kt = f >> 2, tt = f & 3;
            Frag t1;
            #pragma unroll
            for (int j = 0; j < 8; ++j)
                t1.s[j] = f2bf(W1[(kt * 32 + quad * 8 + j) * 64 + tt * 16 + c]);
            sB1[f * 64 + lane] = t1.q;
        }
    }

    // ---- encode: this thread's point, all 16 levels -> sfeat ----
    const int n = blockIdx.x * 512 + tid;
    if (n < N) {
        const float2 xy = ((const float2*)x)[n];
        #pragma unroll 4
        for (int l = 0; l < LVLS; ++l) {
            const float res = RES[l];
            const float sx = xy.x * res, sy = xy.y * res;
            const float fx = floorf(sx),  fy = floorf(sy);
            const float ux = sx - fx,     uy = sy - fy;
            const unsigned ix = (unsigned)(int)fx, iy = (unsigned)(int)fy;
            const unsigned hy0 = iy * PRIME, hy1 = (iy + 1u) * PRIME;
            const unsigned i00 = (ix ^ hy0) & TMASK;
            const unsigned i01 = (ix ^ hy1) & TMASK;
            const float* tbf = tables + (size_t)l * (TSZ * 2u);
            float2 f00, f10, f01, f11;
            if (!(ix & 1u)) {
                // ix even -> i10 = i00^1, i11 = i01^1: each y-row's two corners
                // are an aligned 16 B pair -> one dwordx4 each (2 transactions).
                const f32x4 a = *(const f32x4*)(tbf + 2u * (i00 & ~1u));
                const f32x4 b = *(const f32x4*)(tbf + 2u * (i01 & ~1u));
                const bool s0 = (i00 & 1u) != 0u;
                const bool s1 = (i01 & 1u) != 0u;
                f00 = s0 ? make_float2(a[2], a[3]) : make_float2(a[0], a[1]);
                f10 = s0 ? make_float2(a[0], a[1]) : make_float2(a[2], a[3]);
                f01 = s1 ? make_float2(b[2], b[3]) : make_float2(b[0], b[1]);
                f11 = s1 ? make_float2(b[0], b[1]) : make_float2(b[2], b[3]);
            } else {
                const unsigned i10 = ((ix + 1u) ^ hy0) & TMASK;
                const unsigned i11 = ((ix + 1u) ^ hy1) & TMASK;
                const float2* tb2 = (const float2*)tbf;
                f00 = tb2[i00]; f10 = tb2[i10];
                f01 = tb2[i01]; f11 = tb2[i11];
            }
            const float w00 = (1.f - ux) * (1.f - uy);
            const float w10 = ux * (1.f - uy);
            const float w01 = (1.f - ux) * uy;
            const float w11 = ux * uy;
            const float e0 = w00*f00.x + w10*f10.x + w01*f01.x + w11*f11.x;
            const float e1 = w00*f00.y + w10*f10.y + w01*f01.y + w11*f11.y;
            sfeat[w][l][lane ^ (((l >> 2) & 3) << 4)] = pack2(e0, e1);
        }
    }
    __syncthreads();

    // ---- preload B frags + biases to registers ----
    Frag B0f[4], B1f[8], B2f[2];
    #pragma unroll
    for (int t = 0; t < 4; ++t) B0f[t].q = sB0[t * 64 + lane];
    #pragma unroll
    for (int f = 0; f < 8; ++f) B1f[f].q = sB1[f * 64 + lane];
    #pragma unroll
    for (int f = 0; f < 2; ++f) {
        #pragma unroll
        for (int j = 0; j < 8; ++j) {
            const float v = (c < 3) ? W2[(f * 32 + quad * 8 + j) * 3 + c] : 0.f;
            B2f[f].s[j] = f2bf(v);
        }
    }

    float bias0[4], bias1[4];
    #pragma unroll
    for (int t = 0; t < 4; ++t) { bias0[t] = b0[t * 16 + c]; bias1[t] = b1[t * 16 + c]; }
    const float bias2 = (c < 3) ? b2[c] : 0.f;

    // ---- 4 tiles of 16 points per wave ----
    #pragma unroll 1
    for (int it = 0; it < 4; ++it) {
        const int n0 = blockIdx.x * 512 + w * 64 + it * 16;

        // A0 from sfeat: dword i = levels quad*4+i -> k = quad*8+2i,2i+1
        // read col swizzle: ((quad*4+i)>>2)&3 == quad
        Frag a0;
        #pragma unroll
        for (int i = 0; i < 4; ++i)
            a0.u[i] = sfeat[w][quad * 4 + i][(it * 16 + c) ^ (quad << 4)];

        f32x4 acc0[4];
        #pragma unroll
        for (int t = 0; t < 4; ++t) {
            f32x4 cin = {bias0[t], bias0[t], bias0[t], bias0[t]};
            acc0[t] = __builtin_amdgcn_mfma_f32_16x16x32_bf16(a0.v, B0f[t].v, cin, 0, 0, 0);
        }

        // h1 = relu(acc0) -> LDS scratch [point][neuron]
        lds_fence();
        #pragma unroll
        for (int t = 0; t < 4; ++t)
            #pragma unroll
            for (int rr = 0; rr < 4; ++rr)
                hscr[w][quad * 4 + rr][t * 16 + c] = f2bf(fmaxf(acc0[t][rr], 0.f));

        lds_fence();
        Frag a1[2];
        #pragma unroll
        for (int kt = 0; kt < 2; ++kt)
            a1[kt].q = *(const uint4*)&hscr[w][c][kt * 32 + quad * 8];

        f32x4 acc1[4];
        #pragma unroll
        for (int t = 0; t < 4; ++t) {
            f32x4 cin = {bias1[t], bias1[t], bias1[t], bias1[t]};
            cin = __builtin_amdgcn_mfma_f32_16x16x32_bf16(a1[0].v, B1f[t].v, cin, 0, 0, 0);
            acc1[t] = __builtin_amdgcn_mfma_f32_16x16x32_bf16(a1[1].v, B1f[4 + t].v, cin, 0, 0, 0);
        }

        // h2 = relu(acc1) -> LDS scratch
        lds_fence();
        #pragma unroll
        for (int t = 0; t < 4; ++t)
            #pragma unroll
            for (int rr = 0; rr < 4; ++rr)
                hscr[w][quad * 4 + rr][t * 16 + c] = f2bf(fmaxf(acc1[t][rr], 0.f));

        lds_fence();
        Frag a2[2];
        #pragma unroll
        for (int kt = 0; kt < 2; ++kt)
            a2[kt].q = *(const uint4*)&hscr[w][c][kt * 32 + quad * 8];

        f32x4 cin2 = {bias2, bias2, bias2, bias2};
        cin2 = __builtin_amdgcn_mfma_f32_16x16x32_bf16(a2[0].v, B2f[0].v, cin2, 0, 0, 0);
        f32x4 acc2 = __builtin_amdgcn_mfma_f32_16x16x32_bf16(a2[1].v, B2f[1].v, cin2, 0, 0, 0);

        // sigmoid + store: lane col c<3, rows quad*4+rr
        if (c < 3) {
            #pragma unroll
            for (int rr = 0; rr < 4; ++rr) {
                if (n0 + quad * 4 + rr < N) {
                    const float s = 1.f / (1.f + __expf(-acc2[rr]));
                    out[(size_t)(n0 + quad * 4 + rr) * 3 + c] = s;
                }
            }
        }
    }
}

extern "C" void kernel_launch(void* const* d_in, const int* in_sizes, int n_in,
                              void* d_out, int out_size, void* d_ws, size_t ws_size,
                              hipStream_t stream) {
    const float* x      = (const float*)d_in[0];
    const float* tables = (const float*)d_in[1];
    const float* W0     = (const float*)d_in[2];
    const float* b0     = (const float*)d_in[3];
    const float* W1     = (const float*)d_in[4];
    const float* b1     = (const float*)d_in[5];
    const float* W2     = (const float*)d_in[6];
    const float* b2     = (const float*)d_in[7];
    float* out = (float*)d_out;
    (void)d_ws; (void)ws_size; (void)n_in; (void)out_size;

    const int N  = in_sizes[0] / 2;
    const int PB = (N + 511) / 512;
    ngp_fused<<<PB, 512, 0, stream>>>(x, tables, W0, b0, W1, b1, W2, b2, out, N);
}